// Round 2
// baseline (76.770 us; speedup 1.0000x reference)
//
#include <hip/hip_runtime.h>

typedef __attribute__((ext_vector_type(8))) short bf16x8;
typedef __attribute__((ext_vector_type(4))) float f32x4;

__device__ __forceinline__ unsigned short f2bf(float f) {
  unsigned u = __float_as_uint(f);
  return (unsigned short)((u + 0x7fffu + ((u >> 16) & 1u)) >> 16);
}
__device__ __forceinline__ float bf2f(unsigned short h) {
  return __uint_as_float(((unsigned)h) << 16);
}
__device__ __forceinline__ void gload_lds16(const void* g, void* l) {
  __builtin_amdgcn_global_load_lds((__attribute__((address_space(1))) void*)g,
                                   (__attribute__((address_space(3))) void*)l,
                                   16, 0, 0);
}

// ---------------- conversions ----------------
__global__ __launch_bounds__(256) void convert_x_k(const float* __restrict__ x,
                                                   unsigned short* __restrict__ xb) {
  const int i = blockIdx.x * 256 + threadIdx.x;  // over float4 groups (2097152)
  const float4 v = ((const float4*)x)[i];
  ushort4 o;
  o.x = f2bf(v.x); o.y = f2bf(v.y); o.z = f2bf(v.z); o.w = f2bf(v.w);
  ((ushort4*)xb)[i] = o;
}

__global__ __launch_bounds__(256) void convert_w_k(
    const float* __restrict__ log_dt,
    const float* __restrict__ B_real, const float* __restrict__ B_imag,
    const float* __restrict__ C_real, const float* __restrict__ C_imag,
    const float* __restrict__ W_out,
    unsigned short* __restrict__ W1, unsigned short* __restrict__ W2,
    unsigned short* __restrict__ W3) {
  const int i = blockIdx.x * 256 + threadIdx.x;  // 0..262143
  const float dtv = expf(log_dt[0]);
  if (i < 131072) {
    const int j = i >> 9, h = i & 511;           // W1: (256 x 512), rows = [dt*B_real; dt*B_imag]
    const float v = (j < 128) ? B_real[j * 512 + h] : B_imag[(j - 128) * 512 + h];
    W1[i] = f2bf(dtv * v);
    const int h2 = i >> 8, k = i & 255;          // W2: (512 x 256), cols = [C_real, -C_imag]
    const float v2 = (k < 128) ? C_real[h2 * 128 + k] : -C_imag[h2 * 128 + (k - 128)];
    W2[i] = f2bf(v2);
  }
  W3[i] = f2bf(W_out[i]);                        // W3: (512 x 512) = W_out
}

// ---------------- MFMA GEMM: C[m,j] = sum_k A[m,k] * W[j,k]  (+epilogue) -------------
// MODE 0: store bf16. MODE 1: +epf[col]*bf2f(epx[row,col]), store bf16. MODE 2: +epf[col], store f32.
template <int KT, int MODE>
__global__ __launch_bounds__(256, 2) void gemm_k(
    const unsigned short* __restrict__ A, const unsigned short* __restrict__ Wm,
    void* Cout, const float* epf, const unsigned short* epx, int J) {
  constexpr int K = KT * 64;
  __shared__ unsigned short lds[2 * 16384];  // [2 bufs][A 8192 | W 8192] ushorts = 64 KB
  const int tid = threadIdx.x;
  const int m0 = blockIdx.y * 128;
  const int j0 = blockIdx.x * 128;

  const int r_ = tid >> 3;
  const int sg = tid & 7;

  auto stage = [&](int buf, int kt) {
#pragma unroll
    for (int i = 0; i < 4; ++i) {
      const int r = i * 32 + r_;
      const int sp = sg ^ (r & 7);  // pre-swizzled global source, linear LDS dest
      gload_lds16(A + (long)(m0 + r) * K + kt * 64 + sp * 8,
                  lds + buf * 16384 + i * 2048 + tid * 8);
      gload_lds16(Wm + (long)(j0 + r) * K + kt * 64 + sp * 8,
                  lds + buf * 16384 + 8192 + i * 2048 + tid * 8);
    }
  };

  const int lane = tid & 63;
  const int wid = tid >> 6;
  const int wm = (wid >> 1) * 64;
  const int wn = (wid & 1) * 64;
  const int lrow = lane & 15;
  const int lgrp = lane >> 4;

  f32x4 acc[4][4];
#pragma unroll
  for (int mi = 0; mi < 4; ++mi)
#pragma unroll
    for (int ni = 0; ni < 4; ++ni) acc[mi][ni] = (f32x4){0.f, 0.f, 0.f, 0.f};

  stage(0, 0);
  for (int kt = 0; kt < KT; ++kt) {
    if (kt + 1 < KT) stage((kt + 1) & 1, kt + 1);
    __syncthreads();
    const unsigned short* As = lds + (kt & 1) * 16384;
    const unsigned short* Ws = As + 8192;
#pragma unroll
    for (int kk = 0; kk < 2; ++kk) {
      bf16x8 af[4], wf[4];
#pragma unroll
      for (int mi = 0; mi < 4; ++mi) {
        const int r = wm + mi * 16 + lrow;
        af[mi] = *(const bf16x8*)(As + r * 64 + (((kk * 4 + lgrp) ^ (r & 7)) << 3));
      }
#pragma unroll
      for (int ni = 0; ni < 4; ++ni) {
        const int r = wn + ni * 16 + lrow;
        wf[ni] = *(const bf16x8*)(Ws + r * 64 + (((kk * 4 + lgrp) ^ (r & 7)) << 3));
      }
#pragma unroll
      for (int mi = 0; mi < 4; ++mi)
#pragma unroll
        for (int ni = 0; ni < 4; ++ni)
          acc[mi][ni] = __builtin_amdgcn_mfma_f32_16x16x32_bf16(af[mi], wf[ni],
                                                                acc[mi][ni], 0, 0, 0);
    }
    __syncthreads();
  }

#pragma unroll
  for (int mi = 0; mi < 4; ++mi) {
#pragma unroll
    for (int ni = 0; ni < 4; ++ni) {
      const int row = m0 + wm + mi * 16 + lgrp * 4;
      const int col = j0 + wn + ni * 16 + lrow;
      f32x4 v = acc[mi][ni];
      if (MODE == 0) {
        unsigned short* o = (unsigned short*)Cout;
#pragma unroll
        for (int e = 0; e < 4; ++e) o[(long)(row + e) * J + col] = f2bf(v[e]);
      } else if (MODE == 1) {
        unsigned short* o = (unsigned short*)Cout;
        const float dcol = epf[col];
#pragma unroll
        for (int e = 0; e < 4; ++e) {
          const float xv = bf2f(epx[(long)(row + e) * J + col]);
          o[(long)(row + e) * J + col] = f2bf(v[e] + dcol * xv);
        }
      } else {
        float* o = (float*)Cout;
        const float bo = epf[col];
#pragma unroll
        for (int e = 0; e < 4; ++e) o[(long)(row + e) * J + col] = v[e] + bo;
      }
    }
  }
}

// ---------------- chunked scan with warmup (decay^64 ~ 1e-14 => exact in fp32) -------
__global__ __launch_bounds__(128) void scan_k(
    const unsigned short* __restrict__ Bu, unsigned short* __restrict__ S2,
    const float* __restrict__ log_Lam_real, const float* __restrict__ Lam_imag,
    const float* __restrict__ log_dt, float* __restrict__ finals) {
  __shared__ unsigned short lds[128 * 256];  // 128 timesteps x 256 (r|i) = 64 KB
  const int b = blockIdx.x >> 6;
  const int c = blockIdx.x & 63;
  const int tid = threadIdx.x;  // n in [0,128)

  const int stage_start = (c > 0) ? (c * 64 - 64) : 0;
  const unsigned short* g = Bu + ((long)b * 4096 + stage_start) * 256;
#pragma unroll
  for (int r = 0; r < 32; ++r) gload_lds16(g + r * 1024 + tid * 8, lds + r * 1024 + tid * 8);

  const float dtv = expf(log_dt[0]);
  const float lamr = -expf(log_Lam_real[tid]);
  const float dec = expf(lamr * dtv);
  const float th = Lam_imag[tid] * dtv;
  const float Lr = dec * cosf(th);
  const float Li = dec * sinf(th);

  __syncthreads();

  float sr = 0.f, si = 0.f;
  const int warm = (c > 0) ? 64 : 0;
  for (int i = 0; i < warm; ++i) {
    const float br = bf2f(lds[i * 256 + tid]);
    const float bi = bf2f(lds[i * 256 + 128 + tid]);
    const float nr = Lr * sr - Li * si + br;
    const float ni = Lr * si + Li * sr + bi;
    sr = nr; si = ni;
  }
  const long orow0 = (long)b * 4096 + c * 64;
#pragma unroll 4
  for (int i = 0; i < 64; ++i) {
    const int li = warm + i;
    const float br = bf2f(lds[li * 256 + tid]);
    const float bi = bf2f(lds[li * 256 + 128 + tid]);
    const float nr = Lr * sr - Li * si + br;
    const float ni = Lr * si + Li * sr + bi;
    sr = nr; si = ni;
    unsigned short* o = S2 + (orow0 + i) * 256;
    o[tid] = f2bf(sr);
    o[128 + tid] = f2bf(si);
  }
  if (c == 63) {
    finals[b * 128 + tid] = sr;
    finals[512 + b * 128 + tid] = si;
  }
}

extern "C" void kernel_launch(void* const* d_in, const int* in_sizes, int n_in,
                              void* d_out, int out_size, void* d_ws, size_t ws_size,
                              hipStream_t stream) {
  const float* x      = (const float*)d_in[0];
  const float* logLr  = (const float*)d_in[1];
  const float* LamI   = (const float*)d_in[2];
  const float* B_real = (const float*)d_in[3];
  const float* B_imag = (const float*)d_in[4];
  const float* C_real = (const float*)d_in[5];
  const float* C_imag = (const float*)d_in[6];
  const float* Dv     = (const float*)d_in[7];
  const float* log_dt = (const float*)d_in[8];
  const float* W_out  = (const float*)d_in[9];
  const float* b_out  = (const float*)d_in[10];

  // workspace layout (ushorts). y_bf aliases x_bf (safe: G2 reads x only at its own out elem).
  unsigned short* x_bf = (unsigned short*)d_ws;  // 8388608 elems (16.8 MB), later y_bf
  unsigned short* Bu   = x_bf + 8388608;         // 16384 x 256
  unsigned short* S2   = Bu + 4194304;           // 16384 x 256
  unsigned short* W1   = S2 + 4194304;           // 256 x 512
  unsigned short* W2   = W1 + 131072;            // 512 x 256
  unsigned short* W3   = W2 + 131072;            // 512 x 512

  float* out = (float*)d_out;
  float* finals = out + 8388608;

  convert_x_k<<<8192, 256, 0, stream>>>(x, x_bf);
  convert_w_k<<<1024, 256, 0, stream>>>(log_dt, B_real, B_imag, C_real, C_imag, W_out,
                                        W1, W2, W3);
  // Bu = x @ [dt*B_r; dt*B_i]^T   (M=16384, J=256, K=512)
  gemm_k<8, 0><<<dim3(2, 128), 256, 0, stream>>>(x_bf, W1, Bu, nullptr, nullptr, 256);
  // scan over L in 64-chunks with 64 warmup steps
  scan_k<<<256, 128, 0, stream>>>(Bu, S2, logLr, LamI, log_dt, finals);
  // y = [Sr|Si] @ [C_r, -C_i]^T + D*x   (M=16384, J=512, K=256) -> overwrites x_bf
  gemm_k<4, 1><<<dim3(4, 128), 256, 0, stream>>>(S2, W2, x_bf, Dv, x_bf, 512);
  // out = y @ W_out^T + b_out   (M=16384, J=512, K=512), fp32 store
  gemm_k<8, 2><<<dim3(4, 128), 256, 0, stream>>>(x_bf, W3, out, b_out, nullptr, 512);
}

// Round 5
// 76.388 us; speedup vs baseline: 1.0050x; 1.0050x over previous
//
#include <hip/hip_runtime.h>

typedef __attribute__((ext_vector_type(8))) short bf16x8;
typedef __attribute__((ext_vector_type(4))) float f32x4;

__device__ __forceinline__ unsigned short f2bf(float f) {
  unsigned u = __float_as_uint(f);
  return (unsigned short)((u + 0x7fffu + ((u >> 16) & 1u)) >> 16);
}
__device__ __forceinline__ float bf2f(unsigned short h) {
  return __uint_as_float(((unsigned)h) << 16);
}
__device__ __forceinline__ void gload_lds16(const void* g, void* l) {
  __builtin_amdgcn_global_load_lds((__attribute__((address_space(1))) void*)g,
                                   (__attribute__((address_space(3))) void*)l,
                                   16, 0, 0);
}
__device__ __forceinline__ void drain_vmem() {
  asm volatile("s_waitcnt vmcnt(0)" ::: "memory");
}

// ---------------- conversions / weight prep ----------------
__global__ __launch_bounds__(256) void convert_x_k(const float* __restrict__ x,
                                                   unsigned short* __restrict__ xb) {
  const int i = blockIdx.x * 256 + threadIdx.x;  // over float4 groups (2097152)
  const float4 v = ((const float4*)x)[i];
  ushort4 o;
  o.x = f2bf(v.x); o.y = f2bf(v.y); o.z = f2bf(v.z); o.w = f2bf(v.w);
  ((ushort4*)xb)[i] = o;
}

// W1 (256x512, row stride 512) = dt*[B_real; B_imag]
// W45 (512x768, row stride 768): cols 0..255 = W4 = W_out @ [C_real|-C_imag] (over h),
//                                cols 256..767 = W5 = W_out * D (columnwise)
__global__ __launch_bounds__(256) void prep_k(
    const float* __restrict__ log_dt,
    const float* __restrict__ B_real, const float* __restrict__ B_imag,
    const float* __restrict__ C_real, const float* __restrict__ C_imag,
    const float* __restrict__ W_out, const float* __restrict__ Dv,
    unsigned short* __restrict__ W1, unsigned short* __restrict__ W45) {
  const int bid = blockIdx.x, tid = threadIdx.x;
  if (bid < 512) {
    const float dtv = expf(log_dt[0]);
    const int i = bid * 256 + tid;               // 0..131071
    const int j = i >> 9, h = i & 511;
    const float v = (j < 128) ? B_real[j * 512 + h] : B_imag[(j - 128) * 512 + h];
    W1[i] = f2bf(dtv * v);
  } else if (bid < 1536) {
    const int i = (bid - 512) * 256 + tid;       // 0..262143
    const int j = i >> 9, h = i & 511;
    W45[j * 768 + 256 + h] = f2bf(W_out[i] * Dv[h]);
  } else {
    // W4[j,k] = sum_h W_out[j,h] * (k<128 ? C_real[h,k] : -C_imag[h,k-128])
    const int j0 = (bid - 1536) * 2;             // 256 blocks -> j pairs
    const int k = tid;                            // 0..255
    float a0 = 0.f, a1 = 0.f;
    const float* w0 = W_out + (long)j0 * 512;
    const float* w1 = w0 + 512;
    const float* csrc = (k < 128) ? (C_real + k) : (C_imag + (k - 128));
    const float csgn = (k < 128) ? 1.f : -1.f;
#pragma unroll 8
    for (int h = 0; h < 512; ++h) {
      const float c = csgn * csrc[h * 128];
      a0 += w0[h] * c;
      a1 += w1[h] * c;
    }
    W45[(long)j0 * 768 + k] = f2bf(a0);
    W45[(long)(j0 + 1) * 768 + k] = f2bf(a1);
  }
}

// ---------------- MFMA GEMM: C[m,j] = sum_k A[m,k] * W[j,k], store bf16 -------------
template <int KT>
__global__ __launch_bounds__(256, 2) void gemm_k(
    const unsigned short* __restrict__ A, const unsigned short* __restrict__ Wm,
    unsigned short* __restrict__ Cout, int J) {
  constexpr int K = KT * 64;
  __shared__ unsigned short lds[2 * 16384];  // [2 bufs][A 8192 | W 8192] ushorts = 64 KB
  const int tid = threadIdx.x;
  const int m0 = blockIdx.y * 128;
  const int j0 = blockIdx.x * 128;

  const int r_ = tid >> 3;
  const int sg = tid & 7;

  auto stage = [&](int buf, int kt) {
#pragma unroll
    for (int i = 0; i < 4; ++i) {
      const int r = i * 32 + r_;
      const int sp = sg ^ (r & 7);  // pre-swizzled global source, linear LDS dest
      gload_lds16(A + (long)(m0 + r) * K + kt * 64 + sp * 8,
                  lds + buf * 16384 + i * 2048 + tid * 8);
      gload_lds16(Wm + (long)(j0 + r) * K + kt * 64 + sp * 8,
                  lds + buf * 16384 + 8192 + i * 2048 + tid * 8);
    }
  };

  const int lane = tid & 63;
  const int wid = tid >> 6;
  const int wm = (wid >> 1) * 64;
  const int wn = (wid & 1) * 64;
  const int lrow = lane & 15;
  const int lgrp = lane >> 4;

  f32x4 acc[4][4];
#pragma unroll
  for (int mi = 0; mi < 4; ++mi)
#pragma unroll
    for (int ni = 0; ni < 4; ++ni) acc[mi][ni] = (f32x4){0.f, 0.f, 0.f, 0.f};

  stage(0, 0);
  for (int kt = 0; kt < KT; ++kt) {
    if (kt + 1 < KT) stage((kt + 1) & 1, kt + 1);
    drain_vmem();           // all global_load_lds writes landed before the barrier
    __syncthreads();
    const unsigned short* As = lds + (kt & 1) * 16384;
    const unsigned short* Ws = As + 8192;
#pragma unroll
    for (int kk = 0; kk < 2; ++kk) {
      bf16x8 af[4], wf[4];
#pragma unroll
      for (int mi = 0; mi < 4; ++mi) {
        const int r = wm + mi * 16 + lrow;
        af[mi] = *(const bf16x8*)(As + r * 64 + (((kk * 4 + lgrp) ^ (r & 7)) << 3));
      }
#pragma unroll
      for (int ni = 0; ni < 4; ++ni) {
        const int r = wn + ni * 16 + lrow;
        wf[ni] = *(const bf16x8*)(Ws + r * 64 + (((kk * 4 + lgrp) ^ (r & 7)) << 3));
      }
#pragma unroll
      for (int mi = 0; mi < 4; ++mi)
#pragma unroll
        for (int ni = 0; ni < 4; ++ni)
          acc[mi][ni] = __builtin_amdgcn_mfma_f32_16x16x32_bf16(af[mi], wf[ni],
                                                                acc[mi][ni], 0, 0, 0);
    }
    __syncthreads();
  }

#pragma unroll
  for (int mi = 0; mi < 4; ++mi) {
#pragma unroll
    for (int ni = 0; ni < 4; ++ni) {
      const int row = m0 + wm + mi * 16 + lgrp * 4;
      const int col = j0 + wn + ni * 16 + lrow;
      f32x4 v = acc[mi][ni];
#pragma unroll
      for (int e = 0; e < 4; ++e) Cout[(long)(row + e) * J + col] = f2bf(v[e]);
    }
  }
}

// ------------- fused GEMM: out[m,j] = sum_k [S2|x_bf][m,k] * W45[j,k] + b_out[j] ------
__global__ __launch_bounds__(256, 2) void gemm23_k(
    const unsigned short* __restrict__ S2, const unsigned short* __restrict__ xbf,
    const unsigned short* __restrict__ W45, float* __restrict__ out,
    const float* __restrict__ b_out) {
  constexpr int KT = 12;  // K = 768: kt 0..3 from S2 (stride 256), kt 4..11 from xbf (stride 512)
  __shared__ unsigned short lds[2 * 16384];
  const int tid = threadIdx.x;
  const int m0 = blockIdx.y * 128;
  const int j0 = blockIdx.x * 128;

  const int r_ = tid >> 3;
  const int sg = tid & 7;

  auto stage = [&](int buf, int kt) {
    const unsigned short* asrc;
    long astr;
    int acol;
    if (kt < 4) { asrc = S2; astr = 256; acol = kt * 64; }
    else        { asrc = xbf; astr = 512; acol = (kt - 4) * 64; }
#pragma unroll
    for (int i = 0; i < 4; ++i) {
      const int r = i * 32 + r_;
      const int sp = sg ^ (r & 7);
      gload_lds16(asrc + (long)(m0 + r) * astr + acol + sp * 8,
                  lds + buf * 16384 + i * 2048 + tid * 8);
      gload_lds16(W45 + (long)(j0 + r) * 768 + kt * 64 + sp * 8,
                  lds + buf * 16384 + 8192 + i * 2048 + tid * 8);
    }
  };

  const int lane = tid & 63;
  const int wid = tid >> 6;
  const int wm = (wid >> 1) * 64;
  const int wn = (wid & 1) * 64;
  const int lrow = lane & 15;
  const int lgrp = lane >> 4;

  f32x4 acc[4][4];
#pragma unroll
  for (int mi = 0; mi < 4; ++mi)
#pragma unroll
    for (int ni = 0; ni < 4; ++ni) acc[mi][ni] = (f32x4){0.f, 0.f, 0.f, 0.f};

  stage(0, 0);
  for (int kt = 0; kt < KT; ++kt) {
    if (kt + 1 < KT) stage((kt + 1) & 1, kt + 1);
    drain_vmem();           // all global_load_lds writes landed before the barrier
    __syncthreads();
    const unsigned short* As = lds + (kt & 1) * 16384;
    const unsigned short* Ws = As + 8192;
#pragma unroll
    for (int kk = 0; kk < 2; ++kk) {
      bf16x8 af[4], wf[4];
#pragma unroll
      for (int mi = 0; mi < 4; ++mi) {
        const int r = wm + mi * 16 + lrow;
        af[mi] = *(const bf16x8*)(As + r * 64 + (((kk * 4 + lgrp) ^ (r & 7)) << 3));
      }
#pragma unroll
      for (int ni = 0; ni < 4; ++ni) {
        const int r = wn + ni * 16 + lrow;
        wf[ni] = *(const bf16x8*)(Ws + r * 64 + (((kk * 4 + lgrp) ^ (r & 7)) << 3));
      }
#pragma unroll
      for (int mi = 0; mi < 4; ++mi)
#pragma unroll
        for (int ni = 0; ni < 4; ++ni)
          acc[mi][ni] = __builtin_amdgcn_mfma_f32_16x16x32_bf16(af[mi], wf[ni],
                                                                acc[mi][ni], 0, 0, 0);
    }
    __syncthreads();
  }

#pragma unroll
  for (int mi = 0; mi < 4; ++mi) {
#pragma unroll
    for (int ni = 0; ni < 4; ++ni) {
      const int row = m0 + wm + mi * 16 + lgrp * 4;
      const int col = j0 + wn + ni * 16 + lrow;
      const float bo = b_out[col];
      f32x4 v = acc[mi][ni];
#pragma unroll
      for (int e = 0; e < 4; ++e) out[(long)(row + e) * 512 + col] = v[e] + bo;
    }
  }
}

// ---------------- chunked scan with warmup (decay^64 ~ 1e-14 => exact in fp32) -------
__global__ __launch_bounds__(128) void scan_k(
    const unsigned short* __restrict__ Bu, unsigned short* __restrict__ S2,
    const float* __restrict__ log_Lam_real, const float* __restrict__ Lam_imag,
    const float* __restrict__ log_dt, float* __restrict__ finals) {
  __shared__ unsigned short lds[128 * 256];  // 128 timesteps x 256 (r|i) = 64 KB
  const int b = blockIdx.x >> 6;
  const int c = blockIdx.x & 63;
  const int tid = threadIdx.x;  // n in [0,128)

  const int stage_start = (c > 0) ? (c * 64 - 64) : 0;
  const unsigned short* g = Bu + ((long)b * 4096 + stage_start) * 256;
#pragma unroll
  for (int r = 0; r < 32; ++r) gload_lds16(g + r * 1024 + tid * 8, lds + r * 1024 + tid * 8);

  const float dtv = expf(log_dt[0]);
  const float lamr = -expf(log_Lam_real[tid]);
  const float dec = expf(lamr * dtv);
  const float th = Lam_imag[tid] * dtv;
  const float Lr = dec * cosf(th);
  const float Li = dec * sinf(th);

  drain_vmem();             // all global_load_lds writes landed before the barrier
  __syncthreads();

  float sr = 0.f, si = 0.f;
  const int warm = (c > 0) ? 64 : 0;
  for (int i = 0; i < warm; ++i) {
    const float br = bf2f(lds[i * 256 + tid]);
    const float bi = bf2f(lds[i * 256 + 128 + tid]);
    const float nr = Lr * sr - Li * si + br;
    const float ni = Lr * si + Li * sr + bi;
    sr = nr; si = ni;
  }
  const long orow0 = (long)b * 4096 + c * 64;
#pragma unroll 4
  for (int i = 0; i < 64; ++i) {
    const int li = warm + i;
    const float br = bf2f(lds[li * 256 + tid]);
    const float bi = bf2f(lds[li * 256 + 128 + tid]);
    const float nr = Lr * sr - Li * si + br;
    const float ni = Lr * si + Li * sr + bi;
    sr = nr; si = ni;
    unsigned short* o = S2 + (orow0 + i) * 256;
    o[tid] = f2bf(sr);
    o[128 + tid] = f2bf(si);
  }
  if (c == 63) {
    finals[b * 128 + tid] = sr;
    finals[512 + b * 128 + tid] = si;
  }
}

extern "C" void kernel_launch(void* const* d_in, const int* in_sizes, int n_in,
                              void* d_out, int out_size, void* d_ws, size_t ws_size,
                              hipStream_t stream) {
  const float* x      = (const float*)d_in[0];
  const float* logLr  = (const float*)d_in[1];
  const float* LamI   = (const float*)d_in[2];
  const float* B_real = (const float*)d_in[3];
  const float* B_imag = (const float*)d_in[4];
  const float* C_real = (const float*)d_in[5];
  const float* C_imag = (const float*)d_in[6];
  const float* Dv     = (const float*)d_in[7];
  const float* log_dt = (const float*)d_in[8];
  const float* W_out  = (const float*)d_in[9];
  const float* b_out  = (const float*)d_in[10];

  // workspace layout (ushorts)
  unsigned short* x_bf = (unsigned short*)d_ws;  // 16384 x 512
  unsigned short* Bu   = x_bf + 8388608;         // 16384 x 256
  unsigned short* S2   = Bu + 4194304;           // 16384 x 256
  unsigned short* W1   = S2 + 4194304;           // 256 x 512
  unsigned short* W45  = W1 + 131072;            // 512 x 768

  float* out = (float*)d_out;
  float* finals = out + 8388608;

  convert_x_k<<<8192, 256, 0, stream>>>(x, x_bf);
  prep_k<<<1792, 256, 0, stream>>>(log_dt, B_real, B_imag, C_real, C_imag, W_out, Dv,
                                   W1, W45);
  // Bu = x @ [dt*B_r; dt*B_i]^T   (M=16384, J=256, K=512)
  gemm_k<8><<<dim3(2, 128), 256, 0, stream>>>(x_bf, W1, Bu, 256);
  // scan over L in 64-chunks with 64 warmup steps
  scan_k<<<256, 128, 0, stream>>>(Bu, S2, logLr, LamI, log_dt, finals);
  // out = [S2 | x_bf] @ [W4 | W5]^T + b_out   (M=16384, J=512, K=768), fp32 store
  gemm23_k<<<dim3(4, 128), 256, 0, stream>>>(S2, x_bf, W45, out, b_out);
}

// Round 7
// 66.911 us; speedup vs baseline: 1.1473x; 1.1416x over previous
//
#include <hip/hip_runtime.h>

typedef __attribute__((ext_vector_type(8))) short bf16x8;
typedef __attribute__((ext_vector_type(4))) float f32x4;

__device__ __forceinline__ unsigned short f2bf(float f) {
  unsigned u = __float_as_uint(f);
  return (unsigned short)((u + 0x7fffu + ((u >> 16) & 1u)) >> 16);
}
__device__ __forceinline__ float bf2f(unsigned short h) {
  return __uint_as_float(((unsigned)h) << 16);
}
__device__ __forceinline__ void gload_lds16(const void* g, void* l) {
  __builtin_amdgcn_global_load_lds((__attribute__((address_space(1))) void*)g,
                                   (__attribute__((address_space(3))) void*)l,
                                   16, 0, 0);
}
__device__ __forceinline__ void drain_vmem() {
  asm volatile("s_waitcnt vmcnt(0)" ::: "memory");
}

// ---------------- weight prep ----------------
// W1 (256x512) = dt*[B_real; B_imag]
// W45 (512x768): cols 0..255 = W4 = W_out @ [C_real|-C_imag]; cols 256..767 = W5 = W_out*D
__global__ __launch_bounds__(256) void prep_k(
    const float* __restrict__ log_dt,
    const float* __restrict__ B_real, const float* __restrict__ B_imag,
    const float* __restrict__ C_real, const float* __restrict__ C_imag,
    const float* __restrict__ W_out, const float* __restrict__ Dv,
    unsigned short* __restrict__ W1, unsigned short* __restrict__ W45) {
  const int bid = blockIdx.x, tid = threadIdx.x;
  if (bid < 512) {
    const float dtv = expf(log_dt[0]);
    const int i = bid * 256 + tid;               // 0..131071
    const int j = i >> 9, h = i & 511;
    const float v = (j < 128) ? B_real[j * 512 + h] : B_imag[(j - 128) * 512 + h];
    W1[i] = f2bf(dtv * v);
  } else if (bid < 1536) {
    const int i = (bid - 512) * 256 + tid;       // 0..262143
    const int j = i >> 9, h = i & 511;
    W45[j * 768 + 256 + h] = f2bf(W_out[i] * Dv[h]);
  } else {
    const int j0 = (bid - 1536) * 2;             // 256 blocks -> j pairs
    const int k = tid;                            // 0..255
    float a0 = 0.f, a1 = 0.f;
    const float* w0 = W_out + (long)j0 * 512;
    const float* w1 = w0 + 512;
    const float* csrc = (k < 128) ? (C_real + k) : (C_imag + (k - 128));
    const float csgn = (k < 128) ? 1.f : -1.f;
#pragma unroll 8
    for (int h = 0; h < 512; ++h) {
      const float c = csgn * csrc[h * 128];
      a0 += w0[h] * c;
      a1 += w1[h] * c;
    }
    W45[(long)j0 * 768 + k] = f2bf(a0);
    W45[(long)(j0 + 1) * 768 + k] = f2bf(a1);
  }
}

// ------- fused: Bu-GEMM (96x256 tile, K=512) + bf16(x) byproduct + chunked scan -------
// One block per 64-row output chunk; 32 warmup rows (decay^32 ~ 1e-7, negligible).
__global__ __launch_bounds__(512, 1) void fused1_k(
    const float* __restrict__ x, const unsigned short* __restrict__ W1g,
    unsigned short* __restrict__ xbf, unsigned short* __restrict__ S2,
    const float* __restrict__ log_Lam_real, const float* __restrict__ Lam_imag,
    const float* __restrict__ log_dt, float* __restrict__ finals) {
  // LDS ushort layout: A0 [0,6144) A1 [6144,12288) W0 [12288,28672) W1 [28672,45056)
  // Bu overlay after K-loop: [0, 24576) = 96 rows x 256 cols bf16
  __shared__ unsigned short lds[45056];
  const int tid = threadIdx.x;
  const int c = blockIdx.x, b = c >> 6, cb = c & 63;
  const int warm = cb ? 32 : 0;
  const long base = (long)b * 4096 + (long)cb * 64 - warm;

  // scan parameters (used by tid<128; computed uniformly to start loads early)
  const float dtv = expf(log_dt[0]);
  const int nidx = tid & 127;
  const float lamr = -expf(log_Lam_real[nidx]);
  const float dec = expf(lamr * dtv);
  const float th = Lam_imag[nidx] * dtv;
  const float Lr = dec * cosf(th);
  const float Li = dec * sinf(th);

  const int arow = tid >> 4;   // 0..31
  const int cg = tid & 15;
  float4 areg0, areg1, areg2;
  auto loadA = [&](int kt) {
    const float* xp = x + base * 512 + kt * 64 + cg * 4;
    areg0 = *(const float4*)(xp + (long)arow * 512);
    areg1 = *(const float4*)(xp + (long)(arow + 32) * 512);
    areg2 = *(const float4*)(xp + (long)(arow + 64) * 512);
  };
  auto writeA = [&](int buf, int kt) {
#pragma unroll
    for (int p = 0; p < 3; ++p) {
      const float4 v = (p == 0) ? areg0 : ((p == 1) ? areg1 : areg2);
      const int r = p * 32 + arow;
      ushort4 h;
      h.x = f2bf(v.x); h.y = f2bf(v.y); h.z = f2bf(v.z); h.w = f2bf(v.w);
      const int seg = (cg >> 1) ^ (r & 7);   // XOR-swizzle 16B segments within 128B row
      *(ushort4*)((char*)lds + buf * 12288 + r * 128 + seg * 16 + (cg & 1) * 8) = h;
      *(ushort4*)(xbf + (base + r) * 512 + kt * 64 + cg * 4) = h;  // byproduct (benign dup)
    }
  };
  // global_load_lds: LDS dest MUST be wave-uniform base + lane*16B. Chunk q = i*8+wid
  // covers W rows 8q..8q+7; lane l -> row r = 8q + (l>>3), LDS seg sg = l&7 (linear),
  // global source pre-swizzled: segment sg^(r&7).
  const int wid_ = tid >> 6, lane_ = tid & 63;
  auto stageW = [&](int buf, int kt) {
#pragma unroll
    for (int i = 0; i < 4; ++i) {
      const int q = i * 8 + wid_;          // 0..31
      const int r = q * 8 + (lane_ >> 3);  // W row 0..255
      const int sg = lane_ & 7;
      gload_lds16(W1g + (long)r * 512 + kt * 64 + ((sg ^ (r & 7)) << 3),
                  lds + 12288 + buf * 16384 + q * 512 + lane_ * 8);
    }
  };

  const int lane = tid & 63, wid = tid >> 6;
  const int wm = (wid >> 2) * 48;   // 2 m-waves x 48 rows
  const int wn = (wid & 3) * 64;    // 4 n-waves x 64 cols
  const int lrow = lane & 15, lgrp = lane >> 4;

  f32x4 acc[3][4];
#pragma unroll
  for (int mi = 0; mi < 3; ++mi)
#pragma unroll
    for (int ni = 0; ni < 4; ++ni) acc[mi][ni] = (f32x4){0.f, 0.f, 0.f, 0.f};

  loadA(0); stageW(0, 0); writeA(0, 0);
  drain_vmem();
  __syncthreads();
  int buf = 0;
  for (int kt = 0; kt < 8; ++kt) {
    if (kt < 7) { loadA(kt + 1); stageW(buf ^ 1, kt + 1); }  // in flight during MFMA
    const unsigned short* As = lds + buf * 6144;
    const unsigned short* Ws = lds + 12288 + buf * 16384;
#pragma unroll
    for (int kk = 0; kk < 2; ++kk) {
      bf16x8 af[3], wf[4];
#pragma unroll
      for (int mi = 0; mi < 3; ++mi) {
        const int r = wm + mi * 16 + lrow;
        af[mi] = *(const bf16x8*)(As + r * 64 + (((kk * 4 + lgrp) ^ (r & 7)) << 3));
      }
#pragma unroll
      for (int ni = 0; ni < 4; ++ni) {
        const int r = wn + ni * 16 + lrow;
        wf[ni] = *(const bf16x8*)(Ws + r * 64 + (((kk * 4 + lgrp) ^ (r & 7)) << 3));
      }
#pragma unroll
      for (int mi = 0; mi < 3; ++mi)
#pragma unroll
        for (int ni = 0; ni < 4; ++ni)
          acc[mi][ni] = __builtin_amdgcn_mfma_f32_16x16x32_bf16(af[mi], wf[ni],
                                                                acc[mi][ni], 0, 0, 0);
    }
    if (kt < 7) writeA(buf ^ 1, kt + 1);  // ds_write next A (regs already waited)
    drain_vmem();                          // W gload_lds landed
    __syncthreads();
    buf ^= 1;
  }

  // Bu (acc) -> LDS [96][256] bf16
#pragma unroll
  for (int mi = 0; mi < 3; ++mi)
#pragma unroll
    for (int ni = 0; ni < 4; ++ni)
#pragma unroll
      for (int e = 0; e < 4; ++e) {
        const int row = wm + mi * 16 + lgrp * 4 + e;
        const int col = wn + ni * 16 + lrow;
        lds[row * 256 + col] = f2bf(acc[mi][ni][e]);
      }
  __syncthreads();

  if (tid < 128) {
    float sr = 0.f, si = 0.f;
    for (int i = 0; i < warm; ++i) {
      const float br = bf2f(lds[i * 256 + tid]);
      const float bi = bf2f(lds[i * 256 + 128 + tid]);
      const float nr = Lr * sr - Li * si + br;
      const float ni_ = Lr * si + Li * sr + bi;
      sr = nr; si = ni_;
    }
    const long orow0 = (long)b * 4096 + cb * 64;
#pragma unroll 4
    for (int i = 0; i < 64; ++i) {
      const int li = warm + i;
      const float br = bf2f(lds[li * 256 + tid]);
      const float bi = bf2f(lds[li * 256 + 128 + tid]);
      const float nr = Lr * sr - Li * si + br;
      const float ni_ = Lr * si + Li * sr + bi;
      sr = nr; si = ni_;
      unsigned short* o = S2 + (orow0 + i) * 256;
      o[tid] = f2bf(sr);
      o[128 + tid] = f2bf(si);
    }
    if (cb == 63) {
      finals[b * 128 + tid] = sr;
      finals[512 + b * 128 + tid] = si;
    }
  }
}

// ------------- fused GEMM: out[m,j] = sum_k [S2|x_bf][m,k] * W45[j,k] + b_out[j] ------
__global__ __launch_bounds__(256, 2) void gemm23_k(
    const unsigned short* __restrict__ S2, const unsigned short* __restrict__ xbf,
    const unsigned short* __restrict__ W45, float* __restrict__ out,
    const float* __restrict__ b_out) {
  constexpr int KT = 12;  // K = 768: kt 0..3 from S2 (stride 256), kt 4..11 from xbf (stride 512)
  __shared__ unsigned short lds[2 * 16384];
  const int tid = threadIdx.x;
  const int m0 = blockIdx.y * 128;
  const int j0 = blockIdx.x * 128;

  const int r_ = tid >> 3;
  const int sg = tid & 7;

  auto stage = [&](int buf, int kt) {
    const unsigned short* asrc;
    long astr;
    int acol;
    if (kt < 4) { asrc = S2; astr = 256; acol = kt * 64; }
    else        { asrc = xbf; astr = 512; acol = (kt - 4) * 64; }
#pragma unroll
    for (int i = 0; i < 4; ++i) {
      const int r = i * 32 + r_;
      const int sp = sg ^ (r & 7);
      gload_lds16(asrc + (long)(m0 + r) * astr + acol + sp * 8,
                  lds + buf * 16384 + i * 2048 + tid * 8);
      gload_lds16(W45 + (long)(j0 + r) * 768 + kt * 64 + sp * 8,
                  lds + buf * 16384 + 8192 + i * 2048 + tid * 8);
    }
  };

  const int lane = tid & 63;
  const int wid = tid >> 6;
  const int wm = (wid >> 1) * 64;
  const int wn = (wid & 1) * 64;
  const int lrow = lane & 15;
  const int lgrp = lane >> 4;

  f32x4 acc[4][4];
#pragma unroll
  for (int mi = 0; mi < 4; ++mi)
#pragma unroll
    for (int ni = 0; ni < 4; ++ni) acc[mi][ni] = (f32x4){0.f, 0.f, 0.f, 0.f};

  stage(0, 0);
  drain_vmem();
  __syncthreads();
  int buf = 0;
  for (int kt = 0; kt < KT; ++kt) {
    if (kt + 1 < KT) stage(buf ^ 1, kt + 1);   // in flight during MFMA
    const unsigned short* As = lds + buf * 16384;
    const unsigned short* Ws = As + 8192;
#pragma unroll
    for (int kk = 0; kk < 2; ++kk) {
      bf16x8 af[4], wf[4];
#pragma unroll
      for (int mi = 0; mi < 4; ++mi) {
        const int r = wm + mi * 16 + lrow;
        af[mi] = *(const bf16x8*)(As + r * 64 + (((kk * 4 + lgrp) ^ (r & 7)) << 3));
      }
#pragma unroll
      for (int ni = 0; ni < 4; ++ni) {
        const int r = wn + ni * 16 + lrow;
        wf[ni] = *(const bf16x8*)(Ws + r * 64 + (((kk * 4 + lgrp) ^ (r & 7)) << 3));
      }
#pragma unroll
      for (int mi = 0; mi < 4; ++mi)
#pragma unroll
        for (int ni = 0; ni < 4; ++ni)
          acc[mi][ni] = __builtin_amdgcn_mfma_f32_16x16x32_bf16(af[mi], wf[ni],
                                                                acc[mi][ni], 0, 0, 0);
    }
    drain_vmem();
    __syncthreads();
    buf ^= 1;
  }

#pragma unroll
  for (int mi = 0; mi < 4; ++mi) {
#pragma unroll
    for (int ni = 0; ni < 4; ++ni) {
      const int row = m0 + wm + mi * 16 + lgrp * 4;
      const int col = j0 + wn + ni * 16 + lrow;
      const float bo = b_out[col];
      f32x4 v = acc[mi][ni];
#pragma unroll
      for (int e = 0; e < 4; ++e) out[(long)(row + e) * 512 + col] = v[e] + bo;
    }
  }
}

extern "C" void kernel_launch(void* const* d_in, const int* in_sizes, int n_in,
                              void* d_out, int out_size, void* d_ws, size_t ws_size,
                              hipStream_t stream) {
  const float* x      = (const float*)d_in[0];
  const float* logLr  = (const float*)d_in[1];
  const float* LamI   = (const float*)d_in[2];
  const float* B_real = (const float*)d_in[3];
  const float* B_imag = (const float*)d_in[4];
  const float* C_real = (const float*)d_in[5];
  const float* C_imag = (const float*)d_in[6];
  const float* Dv     = (const float*)d_in[7];
  const float* log_dt = (const float*)d_in[8];
  const float* W_out  = (const float*)d_in[9];
  const float* b_out  = (const float*)d_in[10];

  // workspace layout (ushorts)
  unsigned short* x_bf = (unsigned short*)d_ws;  // 16384 x 512 (byproduct of fused1)
  unsigned short* S2   = x_bf + 8388608;         // 16384 x 256
  unsigned short* W1   = S2 + 4194304;           // 256 x 512
  unsigned short* W45  = W1 + 131072;            // 512 x 768

  float* out = (float*)d_out;
  float* finals = out + 8388608;

  prep_k<<<1792, 256, 0, stream>>>(log_dt, B_real, B_imag, C_real, C_imag, W_out, Dv,
                                   W1, W45);
  // Bu-GEMM + scan fused; writes S2, x_bf, finals
  fused1_k<<<256, 512, 0, stream>>>(x, W1, x_bf, S2, logLr, LamI, log_dt, finals);
  // out = [S2 | x_bf] @ [W4 | W5]^T + b_out   (M=16384, J=512, K=768), fp32 store
  gemm23_k<<<dim3(4, 128), 256, 0, stream>>>(S2, x_bf, W45, out, b_out);
}

// Round 8
// 65.829 us; speedup vs baseline: 1.1662x; 1.0164x over previous
//
#include <hip/hip_runtime.h>

typedef __attribute__((ext_vector_type(8))) short bf16x8;
typedef __attribute__((ext_vector_type(4))) float f32x4;

__device__ __forceinline__ unsigned short f2bf(float f) {
  unsigned u = __float_as_uint(f);
  return (unsigned short)((u + 0x7fffu + ((u >> 16) & 1u)) >> 16);
}
__device__ __forceinline__ float bf2f(unsigned short h) {
  return __uint_as_float(((unsigned)h) << 16);
}
__device__ __forceinline__ void gload_lds16(const void* g, void* l) {
  __builtin_amdgcn_global_load_lds((__attribute__((address_space(1))) void*)g,
                                   (__attribute__((address_space(3))) void*)l,
                                   16, 0, 0);
}
__device__ __forceinline__ void drain_vmem() {
  asm volatile("s_waitcnt vmcnt(0)" ::: "memory");
}

// ---------------- weight prep ----------------
// W1 (256x512) = dt*[B_real; B_imag]
// W45 (512x768): cols 0..255 = W4 = W_out @ [C_real|-C_imag]; cols 256..767 = W5 = W_out*D
__global__ __launch_bounds__(256) void prep_k(
    const float* __restrict__ log_dt,
    const float* __restrict__ B_real, const float* __restrict__ B_imag,
    const float* __restrict__ C_real, const float* __restrict__ C_imag,
    const float* __restrict__ W_out, const float* __restrict__ Dv,
    unsigned short* __restrict__ W1, unsigned short* __restrict__ W45) {
  const int bid = blockIdx.x, tid = threadIdx.x;
  if (bid < 512) {
    const float dtv = expf(log_dt[0]);
    const int i = bid * 256 + tid;               // 0..131071
    const int j = i >> 9, h = i & 511;
    const float v = (j < 128) ? B_real[j * 512 + h] : B_imag[(j - 128) * 512 + h];
    W1[i] = f2bf(dtv * v);
  } else if (bid < 1536) {
    const int i = (bid - 512) * 256 + tid;       // 0..262143
    const int j = i >> 9, h = i & 511;
    W45[j * 768 + 256 + h] = f2bf(W_out[i] * Dv[h]);
  } else {
    const int j0 = (bid - 1536) * 2;             // 256 blocks -> j pairs
    const int k = tid;                            // 0..255
    float a0 = 0.f, a1 = 0.f;
    const float* w0 = W_out + (long)j0 * 512;
    const float* w1 = w0 + 512;
    const float* csrc = (k < 128) ? (C_real + k) : (C_imag + (k - 128));
    const float csgn = (k < 128) ? 1.f : -1.f;
#pragma unroll 8
    for (int h = 0; h < 512; ++h) {
      const float c = csgn * csrc[h * 128];
      a0 += w0[h] * c;
      a1 += w1[h] * c;
    }
    W45[(long)j0 * 768 + k] = f2bf(a0);
    W45[(long)(j0 + 1) * 768 + k] = f2bf(a1);
  }
}

// ------- fused: Bu-GEMM (96x256 tile, K=512) + bf16(x) byproduct + chunked scan -------
// One block per 64-row output chunk; 32 warmup rows (decay^32 ~ 1e-7, negligible).
__global__ __launch_bounds__(512, 1) void fused1_k(
    const float* __restrict__ x, const unsigned short* __restrict__ W1g,
    unsigned short* __restrict__ xbf, unsigned short* __restrict__ S2,
    const float* __restrict__ log_Lam_real, const float* __restrict__ Lam_imag,
    const float* __restrict__ log_dt, float* __restrict__ finals) {
  // LDS ushort layout: A0 [0,6144) A1 [6144,12288) W0 [12288,28672) W1 [28672,45056)
  // Bu overlay after K-loop: [0, 24576) = 96 rows x 256 cols bf16
  __shared__ unsigned short lds[45056];
  const int tid = threadIdx.x;
  const int c = blockIdx.x, b = c >> 6, cb = c & 63;
  const int warm = cb ? 32 : 0;
  const long base = (long)b * 4096 + (long)cb * 64 - warm;

  // scan parameters (used by tid<128; computed uniformly to start loads early)
  const float dtv = expf(log_dt[0]);
  const int nidx = tid & 127;
  const float lamr = -expf(log_Lam_real[nidx]);
  const float dec = expf(lamr * dtv);
  const float th = Lam_imag[nidx] * dtv;
  const float Lr = dec * cosf(th);
  const float Li = dec * sinf(th);

  const int arow = tid >> 4;   // 0..31
  const int cg = tid & 15;
  float4 areg0, areg1, areg2;
  auto loadA = [&](int kt) {
    const float* xp = x + base * 512 + kt * 64 + cg * 4;
    areg0 = *(const float4*)(xp + (long)arow * 512);
    areg1 = *(const float4*)(xp + (long)(arow + 32) * 512);
    areg2 = *(const float4*)(xp + (long)(arow + 64) * 512);
  };
  auto writeA = [&](int buf, int kt) {
#pragma unroll
    for (int p = 0; p < 3; ++p) {
      const float4 v = (p == 0) ? areg0 : ((p == 1) ? areg1 : areg2);
      const int r = p * 32 + arow;
      ushort4 h;
      h.x = f2bf(v.x); h.y = f2bf(v.y); h.z = f2bf(v.z); h.w = f2bf(v.w);
      const int seg = (cg >> 1) ^ (r & 7);   // XOR-swizzle 16B segments within 128B row
      *(ushort4*)((char*)lds + buf * 12288 + r * 128 + seg * 16 + (cg & 1) * 8) = h;
      // warmup rows (p==0, warm>0) are the previous chunk's main rows: skip dup write
      if (p > 0 || warm == 0)
        *(ushort4*)(xbf + (base + r) * 512 + kt * 64 + cg * 4) = h;
    }
  };
  // global_load_lds: LDS dest MUST be wave-uniform base + lane*16B. Chunk q = i*8+wid
  // covers W rows 8q..8q+7; lane l -> row r = 8q + (l>>3), LDS seg sg = l&7 (linear),
  // global source pre-swizzled: segment sg^(r&7).
  const int wid_ = tid >> 6, lane_ = tid & 63;
  auto stageW = [&](int buf, int kt) {
#pragma unroll
    for (int i = 0; i < 4; ++i) {
      const int q = i * 8 + wid_;          // 0..31
      const int r = q * 8 + (lane_ >> 3);  // W row 0..255
      const int sg = lane_ & 7;
      gload_lds16(W1g + (long)r * 512 + kt * 64 + ((sg ^ (r & 7)) << 3),
                  lds + 12288 + buf * 16384 + q * 512 + lane_ * 8);
    }
  };

  const int lane = tid & 63, wid = tid >> 6;
  const int wm = (wid >> 2) * 48;   // 2 m-waves x 48 rows
  const int wn = (wid & 3) * 64;    // 4 n-waves x 64 cols
  const int lrow = lane & 15, lgrp = lane >> 4;

  f32x4 acc[3][4];
#pragma unroll
  for (int mi = 0; mi < 3; ++mi)
#pragma unroll
    for (int ni = 0; ni < 4; ++ni) acc[mi][ni] = (f32x4){0.f, 0.f, 0.f, 0.f};

  loadA(0); stageW(0, 0); writeA(0, 0);
  drain_vmem();
  __syncthreads();
  int buf = 0;
  for (int kt = 0; kt < 8; ++kt) {
    if (kt < 7) { loadA(kt + 1); stageW(buf ^ 1, kt + 1); }  // in flight during MFMA
    const unsigned short* As = lds + buf * 6144;
    const unsigned short* Ws = lds + 12288 + buf * 16384;
#pragma unroll
    for (int kk = 0; kk < 2; ++kk) {
      bf16x8 af[3], wf[4];
#pragma unroll
      for (int mi = 0; mi < 3; ++mi) {
        const int r = wm + mi * 16 + lrow;
        af[mi] = *(const bf16x8*)(As + r * 64 + (((kk * 4 + lgrp) ^ (r & 7)) << 3));
      }
#pragma unroll
      for (int ni = 0; ni < 4; ++ni) {
        const int r = wn + ni * 16 + lrow;
        wf[ni] = *(const bf16x8*)(Ws + r * 64 + (((kk * 4 + lgrp) ^ (r & 7)) << 3));
      }
#pragma unroll
      for (int mi = 0; mi < 3; ++mi)
#pragma unroll
        for (int ni = 0; ni < 4; ++ni)
          acc[mi][ni] = __builtin_amdgcn_mfma_f32_16x16x32_bf16(af[mi], wf[ni],
                                                                acc[mi][ni], 0, 0, 0);
    }
    if (kt < 7) writeA(buf ^ 1, kt + 1);  // ds_write next A (regs already waited)
    drain_vmem();                          // W gload_lds landed
    __syncthreads();
    buf ^= 1;
  }

  // Bu (acc) -> LDS [96][256] bf16
#pragma unroll
  for (int mi = 0; mi < 3; ++mi)
#pragma unroll
    for (int ni = 0; ni < 4; ++ni)
#pragma unroll
      for (int e = 0; e < 4; ++e) {
        const int row = wm + mi * 16 + lgrp * 4 + e;
        const int col = wn + ni * 16 + lrow;
        lds[row * 256 + col] = f2bf(acc[mi][ni][e]);
      }
  __syncthreads();

  if (tid < 128) {
    float sr = 0.f, si = 0.f;
    for (int i = 0; i < warm; ++i) {
      const float br = bf2f(lds[i * 256 + tid]);
      const float bi = bf2f(lds[i * 256 + 128 + tid]);
      const float nr = Lr * sr - Li * si + br;
      const float ni_ = Lr * si + Li * sr + bi;
      sr = nr; si = ni_;
    }
    const long orow0 = (long)b * 4096 + cb * 64;
#pragma unroll 4
    for (int i = 0; i < 64; ++i) {
      const int li = warm + i;
      const float br = bf2f(lds[li * 256 + tid]);
      const float bi = bf2f(lds[li * 256 + 128 + tid]);
      const float nr = Lr * sr - Li * si + br;
      const float ni_ = Lr * si + Li * sr + bi;
      sr = nr; si = ni_;
      unsigned short* o = S2 + (orow0 + i) * 256;
      o[tid] = f2bf(sr);
      o[128 + tid] = f2bf(si);
    }
    if (cb == 63) {
      finals[b * 128 + tid] = sr;
      finals[512 + b * 128 + tid] = si;
    }
  }
}

// ------------- fused GEMM: out[m,j] = sum_k [S2|x_bf][m,k] * W45[j,k] + b_out[j] ------
// Tile 128m x 256j, 512 threads (2m x 4n waves), grid 256, XCD-chunked swizzle.
__global__ __launch_bounds__(512, 1) void gemm23_k(
    const unsigned short* __restrict__ S2, const unsigned short* __restrict__ xbf,
    const unsigned short* __restrict__ W45, float* __restrict__ out,
    const float* __restrict__ b_out) {
  constexpr int KT = 12;  // K = 768: kt 0..3 from S2 (stride 256), kt 4..11 from xbf (stride 512)
  // LDS ushorts per buf: A [0,8192) = 128x64, W [8192,24576) = 256x64; 2 bufs = 96 KB
  __shared__ unsigned short lds[49152];
  const int tid = threadIdx.x;
  const int id = blockIdx.x;                    // 0..255
  const int swz = (id & 7) * 32 + (id >> 3);    // bijective XCD-chunk (256 = 8*32)
  const int m0 = (swz >> 1) * 128;
  const int j0 = (swz & 1) * 256;

  const int r8 = tid >> 3;   // 0..63
  const int sg = tid & 7;

  auto stage = [&](int buf, int kt) {
    const unsigned short* asrc;
    long astr;
    int acol;
    if (kt < 4) { asrc = S2; astr = 256; acol = kt * 64; }
    else        { asrc = xbf; astr = 512; acol = (kt - 4) * 64; }
#pragma unroll
    for (int i = 0; i < 2; ++i) {
      const int r = i * 64 + r8;
      const int sp = sg ^ (r & 7);
      gload_lds16(asrc + (long)(m0 + r) * astr + acol + sp * 8,
                  lds + buf * 24576 + i * 4096 + tid * 8);
    }
#pragma unroll
    for (int i = 0; i < 4; ++i) {
      const int r = i * 64 + r8;
      const int sp = sg ^ (r & 7);
      gload_lds16(W45 + (long)(j0 + r) * 768 + kt * 64 + sp * 8,
                  lds + buf * 24576 + 8192 + i * 4096 + tid * 8);
    }
  };

  const int lane = tid & 63;
  const int wid = tid >> 6;          // 8 waves
  const int wm = (wid >> 2) * 64;    // 2 m-waves x 64 rows
  const int wn = (wid & 3) * 64;     // 4 n-waves x 64 cols
  const int lrow = lane & 15;
  const int lgrp = lane >> 4;

  f32x4 acc[4][4];
#pragma unroll
  for (int mi = 0; mi < 4; ++mi)
#pragma unroll
    for (int ni = 0; ni < 4; ++ni) acc[mi][ni] = (f32x4){0.f, 0.f, 0.f, 0.f};

  stage(0, 0);
  drain_vmem();
  __syncthreads();
  int buf = 0;
  for (int kt = 0; kt < KT; ++kt) {
    if (kt + 1 < KT) stage(buf ^ 1, kt + 1);   // in flight during MFMA
    const unsigned short* As = lds + buf * 24576;
    const unsigned short* Ws = As + 8192;
#pragma unroll
    for (int kk = 0; kk < 2; ++kk) {
      bf16x8 af[4], wf[4];
#pragma unroll
      for (int mi = 0; mi < 4; ++mi) {
        const int r = wm + mi * 16 + lrow;
        af[mi] = *(const bf16x8*)(As + r * 64 + (((kk * 4 + lgrp) ^ (r & 7)) << 3));
      }
#pragma unroll
      for (int ni = 0; ni < 4; ++ni) {
        const int r = wn + ni * 16 + lrow;
        wf[ni] = *(const bf16x8*)(Ws + r * 64 + (((kk * 4 + lgrp) ^ (r & 7)) << 3));
      }
#pragma unroll
      for (int mi = 0; mi < 4; ++mi)
#pragma unroll
        for (int ni = 0; ni < 4; ++ni)
          acc[mi][ni] = __builtin_amdgcn_mfma_f32_16x16x32_bf16(af[mi], wf[ni],
                                                                acc[mi][ni], 0, 0, 0);
    }
    drain_vmem();
    __syncthreads();
    buf ^= 1;
  }

#pragma unroll
  for (int mi = 0; mi < 4; ++mi) {
#pragma unroll
    for (int ni = 0; ni < 4; ++ni) {
      const int row = m0 + wm + mi * 16 + lgrp * 4;
      const int col = j0 + wn + ni * 16 + lrow;
      const float bo = b_out[col];
      f32x4 v = acc[mi][ni];
#pragma unroll
      for (int e = 0; e < 4; ++e) out[(long)(row + e) * 512 + col] = v[e] + bo;
    }
  }
}

extern "C" void kernel_launch(void* const* d_in, const int* in_sizes, int n_in,
                              void* d_out, int out_size, void* d_ws, size_t ws_size,
                              hipStream_t stream) {
  const float* x      = (const float*)d_in[0];
  const float* logLr  = (const float*)d_in[1];
  const float* LamI   = (const float*)d_in[2];
  const float* B_real = (const float*)d_in[3];
  const float* B_imag = (const float*)d_in[4];
  const float* C_real = (const float*)d_in[5];
  const float* C_imag = (const float*)d_in[6];
  const float* Dv     = (const float*)d_in[7];
  const float* log_dt = (const float*)d_in[8];
  const float* W_out  = (const float*)d_in[9];
  const float* b_out  = (const float*)d_in[10];

  // workspace layout (ushorts)
  unsigned short* x_bf = (unsigned short*)d_ws;  // 16384 x 512 (byproduct of fused1)
  unsigned short* S2   = x_bf + 8388608;         // 16384 x 256
  unsigned short* W1   = S2 + 4194304;           // 256 x 512
  unsigned short* W45  = W1 + 131072;            // 512 x 768

  float* out = (float*)d_out;
  float* finals = out + 8388608;

  prep_k<<<1792, 256, 0, stream>>>(log_dt, B_real, B_imag, C_real, C_imag, W_out, Dv,
                                   W1, W45);
  // Bu-GEMM + scan fused; writes S2, x_bf, finals
  fused1_k<<<256, 512, 0, stream>>>(x, W1, x_bf, S2, logLr, LamI, log_dt, finals);
  // out = [S2 | x_bf] @ [W4 | W5]^T + b_out   (M=16384, J=512, K=768), fp32 store
  gemm23_k<<<256, 512, 0, stream>>>(S2, x_bf, W45, out, b_out);
}

// Round 9
// 55.013 us; speedup vs baseline: 1.3955x; 1.1966x over previous
//
#include <hip/hip_runtime.h>

typedef __attribute__((ext_vector_type(8))) short bf16x8;
typedef __attribute__((ext_vector_type(4))) float f32x4;

__device__ __forceinline__ unsigned short f2bf(float f) {
  unsigned u = __float_as_uint(f);
  return (unsigned short)((u + 0x7fffu + ((u >> 16) & 1u)) >> 16);
}
__device__ __forceinline__ float bf2f(unsigned short h) {
  return __uint_as_float(((unsigned)h) << 16);
}
__device__ __forceinline__ void gload_lds16(const void* g, void* l) {
  __builtin_amdgcn_global_load_lds((__attribute__((address_space(1))) void*)g,
                                   (__attribute__((address_space(3))) void*)l,
                                   16, 0, 0);
}
#define VMCNT(n) asm volatile("s_waitcnt vmcnt(" #n ")" ::: "memory")
#define LGKM0() asm volatile("s_waitcnt lgkmcnt(0)" ::: "memory")
#define SB0() __builtin_amdgcn_sched_barrier(0)
#define BAR() __builtin_amdgcn_s_barrier()

// ---------------- weight prep ----------------
// W1 (256x512) = dt*[B_real; B_imag]
// W45 (512x768): cols 0..255 = W4 = W_out @ [C_real|-C_imag]; cols 256..767 = W5 = W_out*D
__global__ __launch_bounds__(256) void prep_k(
    const float* __restrict__ log_dt,
    const float* __restrict__ B_real, const float* __restrict__ B_imag,
    const float* __restrict__ C_real, const float* __restrict__ C_imag,
    const float* __restrict__ W_out, const float* __restrict__ Dv,
    unsigned short* __restrict__ W1, unsigned short* __restrict__ W45) {
  __shared__ float4 red[4][2][64];  // 8 KB
  const int bid = blockIdx.x, tid = threadIdx.x;
  if (bid < 512) {
    const float dtv = expf(log_dt[0]);
    const int i = bid * 256 + tid;               // 0..131071
    const int j = i >> 9, h = i & 511;
    const float v = (j < 128) ? B_real[j * 512 + h] : B_imag[(j - 128) * 512 + h];
    W1[i] = f2bf(dtv * v);
  } else if (bid < 1536) {
    const int i = (bid - 512) * 256 + tid;       // 0..262143
    const int j = i >> 9, h = i & 511;
    W45[j * 768 + 256 + h] = f2bf(W_out[i] * Dv[h]);
  } else {
    // W4[j,k] = sum_h W_out[j,h] * (k<128 ? C_real[h,k] : -C_imag[h,k-128])
    // 256 threads = 64 k-float4-groups x 4 h-chunks; LDS partial reduce.
    const int j0 = (bid - 1536) * 2;
    const int kg = tid & 63;                     // float4 group: k = 4*kg
    const int hc = tid >> 6;                     // 0..3
    const int k4 = kg * 4;
    const bool im = (kg >= 32);
    const float* cbase = im ? (C_imag + (k4 - 128)) : (C_real + k4);
    const float* w0 = W_out + (long)j0 * 512;
    const float* w1 = w0 + 512;
    float4 acc0 = {0.f, 0.f, 0.f, 0.f}, acc1 = {0.f, 0.f, 0.f, 0.f};
#pragma unroll 8
    for (int hh = 0; hh < 128; ++hh) {
      const int h = hc * 128 + hh;
      const float4 cv = *(const float4*)(cbase + (long)h * 128);
      const float s0 = w0[h], s1 = w1[h];
      acc0.x += cv.x * s0; acc0.y += cv.y * s0; acc0.z += cv.z * s0; acc0.w += cv.w * s0;
      acc1.x += cv.x * s1; acc1.y += cv.y * s1; acc1.z += cv.z * s1; acc1.w += cv.w * s1;
    }
    if (im) {
      acc0.x = -acc0.x; acc0.y = -acc0.y; acc0.z = -acc0.z; acc0.w = -acc0.w;
      acc1.x = -acc1.x; acc1.y = -acc1.y; acc1.z = -acc1.z; acc1.w = -acc1.w;
    }
    red[hc][0][kg] = acc0;
    red[hc][1][kg] = acc1;
    __syncthreads();
    if (tid < 128) {
      const int r = tid >> 6, g = tid & 63;
      float4 s = red[0][r][g];
      const float4 s1 = red[1][r][g], s2 = red[2][r][g], s3 = red[3][r][g];
      s.x += s1.x + s2.x + s3.x; s.y += s1.y + s2.y + s3.y;
      s.z += s1.z + s2.z + s3.z; s.w += s1.w + s2.w + s3.w;
      unsigned short* o = W45 + (long)(j0 + r) * 768 + g * 4;
      o[0] = f2bf(s.x); o[1] = f2bf(s.y); o[2] = f2bf(s.z); o[3] = f2bf(s.w);
    }
  }
}

// ------- fused: Bu-GEMM (96x256 tile, K=512) + bf16(x) byproduct + chunked scan -------
// Pipelined: 3 reg-sets for x-loads (3 steps ahead), W-stage + A-ds_write before MFMA,
// raw barrier + counted vmcnt (no full drain mid-loop).
__global__ __launch_bounds__(512, 1) void fused1_k(
    const float* __restrict__ x, const unsigned short* __restrict__ W1g,
    unsigned short* __restrict__ xbf, unsigned short* __restrict__ S2,
    const float* __restrict__ log_Lam_real, const float* __restrict__ Lam_imag,
    const float* __restrict__ log_dt, float* __restrict__ finals) {
  // LDS ushort: A0 [0,6144) A1 [6144,12288) W0 [12288,28672) W1 [28672,45056)
  __shared__ unsigned short lds[45056];
  const int tid = threadIdx.x;
  const int c = blockIdx.x, b = c >> 6, cb = c & 63;
  const int warm = cb ? 32 : 0;
  const long base = (long)b * 4096 + (long)cb * 64 - warm;

  const float dtv = expf(log_dt[0]);
  const int nidx = tid & 127;
  const float lamr = -expf(log_Lam_real[nidx]);
  const float dec = expf(lamr * dtv);
  const float th = Lam_imag[nidx] * dtv;
  const float Lr = dec * cosf(th);
  const float Li = dec * sinf(th);

  const int arow = tid >> 4;   // 0..31
  const int cg = tid & 15;
  const int wid_ = tid >> 6, lane_ = tid & 63;

  float4 a0S0, a1S0, a2S0, a0S1, a1S1, a2S1, a0S2, a1S2, a2S2;

#define LOADA(S, kt) {                                                   \
    const float* xp = x + base * 512 + (kt) * 64 + cg * 4;               \
    a0##S = *(const float4*)(xp + (long)arow * 512);                     \
    a1##S = *(const float4*)(xp + (long)(arow + 32) * 512);              \
    a2##S = *(const float4*)(xp + (long)(arow + 64) * 512); }

#define WRA1(V, R, buf, kt, DOX) {                                       \
    ushort4 hh_; hh_.x = f2bf(V.x); hh_.y = f2bf(V.y);                   \
    hh_.z = f2bf(V.z); hh_.w = f2bf(V.w);                                \
    const int seg_ = (cg >> 1) ^ ((R) & 7);                              \
    *(ushort4*)((char*)lds + (buf) * 12288 + (R) * 128 + seg_ * 16 +     \
                (cg & 1) * 8) = hh_;                                     \
    if (DOX) *(ushort4*)(xbf + (base + (R)) * 512 + (kt) * 64 + cg * 4) = hh_; }

#define WRITEA(S, buf, kt) {                                             \
    WRA1(a0##S, arow, buf, kt, (warm == 0));                             \
    WRA1(a1##S, arow + 32, buf, kt, 1);                                  \
    WRA1(a2##S, arow + 64, buf, kt, 1); }

  auto stageW = [&](int buf, int kt) {
#pragma unroll
    for (int i = 0; i < 4; ++i) {
      const int q = i * 8 + wid_;          // 0..31
      const int r = q * 8 + (lane_ >> 3);  // W row 0..255
      const int sg = lane_ & 7;
      gload_lds16(W1g + (long)r * 512 + kt * 64 + ((sg ^ (r & 7)) << 3),
                  lds + 12288 + buf * 16384 + q * 512 + lane_ * 8);
    }
  };

  const int lane = tid & 63, wid = tid >> 6;
  const int wm = (wid >> 2) * 48;   // 2 m-waves x 48 rows
  const int wn = (wid & 3) * 64;    // 4 n-waves x 64 cols
  const int lrow = lane & 15, lgrp = lane >> 4;

  f32x4 acc[3][4];
#pragma unroll
  for (int mi = 0; mi < 3; ++mi)
#pragma unroll
    for (int ni = 0; ni < 4; ++ni) acc[mi][ni] = (f32x4){0.f, 0.f, 0.f, 0.f};

  auto mfma_step = [&](int buf) {
    const unsigned short* As = lds + buf * 6144;
    const unsigned short* Ws = lds + 12288 + buf * 16384;
#pragma unroll
    for (int kk = 0; kk < 2; ++kk) {
      bf16x8 af[3], wf[4];
#pragma unroll
      for (int mi = 0; mi < 3; ++mi) {
        const int r = wm + mi * 16 + lrow;
        af[mi] = *(const bf16x8*)(As + r * 64 + (((kk * 4 + lgrp) ^ (r & 7)) << 3));
      }
#pragma unroll
      for (int ni = 0; ni < 4; ++ni) {
        const int r = wn + ni * 16 + lrow;
        wf[ni] = *(const bf16x8*)(Ws + r * 64 + (((kk * 4 + lgrp) ^ (r & 7)) << 3));
      }
#pragma unroll
      for (int mi = 0; mi < 3; ++mi)
#pragma unroll
        for (int ni = 0; ni < 4; ++ni)
          acc[mi][ni] = __builtin_amdgcn_mfma_f32_16x16x32_bf16(af[mi], wf[ni],
                                                                acc[mi][ni], 0, 0, 0);
    }
  };

  // prologue: A(0) staged+written, A(1),A(2) in flight
  LOADA(S0, 0);
  stageW(0, 0);
  WRITEA(S0, 0, 0);
  LOADA(S1, 1);
  LOADA(S2, 2);
  VMCNT(6);  // stageW(0)+stores drained; A(1),A(2) loads in flight
  LGKM0();
  SB0(); BAR(); SB0();

#pragma unroll
  for (int kt = 0; kt < 8; ++kt) {
    if (kt < 7) {
      stageW((kt & 1) ^ 1, kt + 1);
      // WRITEA set (kt+1)%3 holds A(kt+1) (loaded 2+ iters ago)
      if (((kt + 1) % 3) == 0) { WRITEA(S0, (kt & 1) ^ 1, kt + 1); }
      else if (((kt + 1) % 3) == 1) { WRITEA(S1, (kt & 1) ^ 1, kt + 1); }
      else { WRITEA(S2, (kt & 1) ^ 1, kt + 1); }
    }
    if (kt < 5) {
      // LOADA set kt%3 <- A(kt+3)
      if ((kt % 3) == 0) { LOADA(S0, kt + 3); }
      else if ((kt % 3) == 1) { LOADA(S1, kt + 3); }
      else { LOADA(S2, kt + 3); }
    }
    mfma_step(kt & 1);
    if (kt < 5) { VMCNT(3); }         // stageW(kt+1)+stores done; newest LOADA flies
    else if (kt < 7) { VMCNT(0); }    // tail: drain staging
    if (kt < 7) { LGKM0(); SB0(); BAR(); SB0(); }
  }
  __syncthreads();  // all MFMA(7) reads done before Bu overlay

  // Bu (acc) -> LDS [96][256] bf16
#pragma unroll
  for (int mi = 0; mi < 3; ++mi)
#pragma unroll
    for (int ni = 0; ni < 4; ++ni)
#pragma unroll
      for (int e = 0; e < 4; ++e) {
        const int row = wm + mi * 16 + lgrp * 4 + e;
        const int col = wn + ni * 16 + lrow;
        lds[row * 256 + col] = f2bf(acc[mi][ni][e]);
      }
  __syncthreads();

  if (tid < 128) {
    float sr = 0.f, si = 0.f;
    for (int i = 0; i < warm; ++i) {
      const float br = bf2f(lds[i * 256 + tid]);
      const float bi = bf2f(lds[i * 256 + 128 + tid]);
      const float nr = Lr * sr - Li * si + br;
      const float ni_ = Lr * si + Li * sr + bi;
      sr = nr; si = ni_;
    }
    const long orow0 = (long)b * 4096 + cb * 64;
#pragma unroll 4
    for (int i = 0; i < 64; ++i) {
      const int li = warm + i;
      const float br = bf2f(lds[li * 256 + tid]);
      const float bi = bf2f(lds[li * 256 + 128 + tid]);
      const float nr = Lr * sr - Li * si + br;
      const float ni_ = Lr * si + Li * sr + bi;
      sr = nr; si = ni_;
      unsigned short* o = S2 + (orow0 + i) * 256;
      o[tid] = f2bf(sr);
      o[128 + tid] = f2bf(si);
    }
    if (cb == 63) {
      finals[b * 128 + tid] = sr;
      finals[512 + b * 128 + tid] = si;
    }
  }
#undef LOADA
#undef WRA1
#undef WRITEA
}

// ------------- fused GEMM: out[m,j] = sum_k [S2|x_bf][m,k] * W45[j,k] + b_out[j] ------
// Tile 128m x 256j, 512 threads, 3 LDS bufs (144 KB), stage 2 ahead, counted vmcnt.
__global__ __launch_bounds__(512, 1) void gemm23_k(
    const unsigned short* __restrict__ S2, const unsigned short* __restrict__ xbf,
    const unsigned short* __restrict__ W45, float* __restrict__ out,
    const float* __restrict__ b_out) {
  constexpr int KT = 12;  // K=768: kt 0..3 from S2 (stride 256), kt 4..11 from xbf (512)
  __shared__ unsigned short lds[73728];  // 3 x 24576 ushorts = 144 KB
  const int tid = threadIdx.x;
  const int id = blockIdx.x;                    // 0..255
  const int swz = (id & 7) * 32 + (id >> 3);    // bijective XCD-chunk (256 = 8*32)
  const int m0 = (swz >> 1) * 128;
  const int j0 = (swz & 1) * 256;

  const int r8 = tid >> 3;   // 0..63
  const int sg = tid & 7;

  auto stage = [&](int buf, int kt) {
    const unsigned short* asrc;
    long astr;
    int acol;
    if (kt < 4) { asrc = S2; astr = 256; acol = kt * 64; }
    else        { asrc = xbf; astr = 512; acol = (kt - 4) * 64; }
#pragma unroll
    for (int i = 0; i < 2; ++i) {
      const int r = i * 64 + r8;
      const int sp = sg ^ (r & 7);
      gload_lds16(asrc + (long)(m0 + r) * astr + acol + sp * 8,
                  lds + buf * 24576 + i * 4096 + tid * 8);
    }
#pragma unroll
    for (int i = 0; i < 4; ++i) {
      const int r = i * 64 + r8;
      const int sp = sg ^ (r & 7);
      gload_lds16(W45 + (long)(j0 + r) * 768 + kt * 64 + sp * 8,
                  lds + buf * 24576 + 8192 + i * 4096 + tid * 8);
    }
  };

  const int lane = tid & 63;
  const int wid = tid >> 6;          // 8 waves
  const int wm = (wid >> 2) * 64;    // 2 m-waves x 64 rows
  const int wn = (wid & 3) * 64;     // 4 n-waves x 64 cols
  const int lrow = lane & 15;
  const int lgrp = lane >> 4;

  f32x4 acc[4][4];
#pragma unroll
  for (int mi = 0; mi < 4; ++mi)
#pragma unroll
    for (int ni = 0; ni < 4; ++ni) acc[mi][ni] = (f32x4){0.f, 0.f, 0.f, 0.f};

  stage(0, 0);
  stage(1, 1);
  VMCNT(6);  // stage(0) landed; stage(1) in flight
  SB0(); BAR(); SB0();

#pragma unroll
  for (int kt = 0; kt < KT; ++kt) {
    if (kt + 2 < KT) stage((kt + 2) % 3, kt + 2);
    const unsigned short* As = lds + (kt % 3) * 24576;
    const unsigned short* Ws = As + 8192;
#pragma unroll
    for (int kk = 0; kk < 2; ++kk) {
      bf16x8 af[4], wf[4];
#pragma unroll
      for (int mi = 0; mi < 4; ++mi) {
        const int r = wm + mi * 16 + lrow;
        af[mi] = *(const bf16x8*)(As + r * 64 + (((kk * 4 + lgrp) ^ (r & 7)) << 3));
      }
#pragma unroll
      for (int ni = 0; ni < 4; ++ni) {
        const int r = wn + ni * 16 + lrow;
        wf[ni] = *(const bf16x8*)(Ws + r * 64 + (((kk * 4 + lgrp) ^ (r & 7)) << 3));
      }
#pragma unroll
      for (int mi = 0; mi < 4; ++mi)
#pragma unroll
        for (int ni = 0; ni < 4; ++ni)
          acc[mi][ni] = __builtin_amdgcn_mfma_f32_16x16x32_bf16(af[mi], wf[ni],
                                                                acc[mi][ni], 0, 0, 0);
    }
    if (kt + 2 < KT) { VMCNT(6); }       // stage(kt+1) landed; stage(kt+2) flies
    else if (kt == KT - 2) { VMCNT(0); } // last stage must land
    if (kt < KT - 1) { SB0(); BAR(); SB0(); }
  }

#pragma unroll
  for (int mi = 0; mi < 4; ++mi) {
#pragma unroll
    for (int ni = 0; ni < 4; ++ni) {
      const int row = m0 + wm + mi * 16 + lgrp * 4;
      const int col = j0 + wn + ni * 16 + lrow;
      const float bo = b_out[col];
      f32x4 v = acc[mi][ni];
#pragma unroll
      for (int e = 0; e < 4; ++e) out[(long)(row + e) * 512 + col] = v[e] + bo;
    }
  }
}

extern "C" void kernel_launch(void* const* d_in, const int* in_sizes, int n_in,
                              void* d_out, int out_size, void* d_ws, size_t ws_size,
                              hipStream_t stream) {
  const float* x      = (const float*)d_in[0];
  const float* logLr  = (const float*)d_in[1];
  const float* LamI   = (const float*)d_in[2];
  const float* B_real = (const float*)d_in[3];
  const float* B_imag = (const float*)d_in[4];
  const float* C_real = (const float*)d_in[5];
  const float* C_imag = (const float*)d_in[6];
  const float* Dv     = (const float*)d_in[7];
  const float* log_dt = (const float*)d_in[8];
  const float* W_out  = (const float*)d_in[9];
  const float* b_out  = (const float*)d_in[10];

  // workspace layout (ushorts)
  unsigned short* x_bf = (unsigned short*)d_ws;  // 16384 x 512 (byproduct of fused1)
  unsigned short* S2   = x_bf + 8388608;         // 16384 x 256
  unsigned short* W1   = S2 + 4194304;           // 256 x 512
  unsigned short* W45  = W1 + 131072;            // 512 x 768

  float* out = (float*)d_out;
  float* finals = out + 8388608;

  prep_k<<<1792, 256, 0, stream>>>(log_dt, B_real, B_imag, C_real, C_imag, W_out, Dv,
                                   W1, W45);
  // Bu-GEMM + scan fused; writes S2, x_bf, finals
  fused1_k<<<256, 512, 0, stream>>>(x, W1, x_bf, S2, logLr, LamI, log_dt, finals);
  // out = [S2 | x_bf] @ [W4 | W5]^T + b_out   (M=16384, J=512, K=768), fp32 store
  gemm23_k<<<256, 512, 0, stream>>>(S2, x_bf, W45, out, b_out);
}